// Round 4
// baseline (231.686 us; speedup 1.0000x reference)
//
#include <hip/hip_runtime.h>
#include <stdint.h>
#include <stddef.h>

typedef unsigned short u16;
typedef unsigned int   u32;

typedef __attribute__((ext_vector_type(8))) short bf16x8;
typedef __attribute__((ext_vector_type(4))) float f32x4;

__device__ __forceinline__ float b2f(u16 u)    { return __uint_as_float(((u32)u) << 16); }
__device__ __forceinline__ float b2f_lo(u32 v) { return __uint_as_float(v << 16); }
__device__ __forceinline__ float b2f_hi(u32 v) { return __uint_as_float(v & 0xFFFF0000u); }
__device__ __forceinline__ u16 f2b(float f){
  u32 x = __float_as_uint(f);
  return (u16)((x + 0x7FFFu + ((x >> 16) & 1u)) >> 16);
}

// ---------------------------------------------------------------------------
// K0a: x[b][c][w] FLOAT32 -> xt[b][w][c] bf16 (fused transpose+downconvert).
// B=4, C=256, W=8192.  grid (128 w-tiles, 4 c-tiles, 4 b) x 256 thr; 64x64 tile.
// ---------------------------------------------------------------------------
__global__ __launch_bounds__(256) void k_transpose(const float* __restrict__ x, u16* __restrict__ xt){
  __shared__ u16 tile[64 * 65];
  const int wt = blockIdx.x, ct = blockIdx.y, b = blockIdx.z;
  const int W0 = wt << 6, C0 = ct << 6;
  const int t = threadIdx.x;
#pragma unroll
  for (int it = 0; it < 4; ++it){
    const int task = t + (it << 8);          // 0..1023
    const int c = task >> 4, u = task & 15;  // c<64, u<16 (float4 chunks of 64-wide row)
    const float4 d = *(const float4*)(x + ((size_t)((b << 8) + C0 + c) << 13) + W0 + (u << 2));
    const int base = c * 65 + (u << 2);
    tile[base + 0] = f2b(d.x); tile[base + 1] = f2b(d.y);
    tile[base + 2] = f2b(d.z); tile[base + 3] = f2b(d.w);
  }
  __syncthreads();
#pragma unroll
  for (int it = 0; it < 2; ++it){
    const int task = t + (it << 8);          // 0..511
    const int wr = task >> 3, cu = task & 7; // wr<64, cu<8 (8 bf16 per chunk)
    const int cb = cu << 3;
    u32 a0 = (u32)tile[(cb + 0) * 65 + wr] | ((u32)tile[(cb + 1) * 65 + wr] << 16);
    u32 a1 = (u32)tile[(cb + 2) * 65 + wr] | ((u32)tile[(cb + 3) * 65 + wr] << 16);
    u32 a2 = (u32)tile[(cb + 4) * 65 + wr] | ((u32)tile[(cb + 5) * 65 + wr] << 16);
    u32 a3 = (u32)tile[(cb + 6) * 65 + wr] | ((u32)tile[(cb + 7) * 65 + wr] << 16);
    uint4 val = make_uint4(a0, a1, a2, a3);
    *(uint4*)(xt + ((size_t)((b << 13) + W0 + wr) << 8) + C0 + cb) = val;
  }
}

// ---------------------------------------------------------------------------
// K0b: build combined weight matrix Wall[896][256] (bf16) + fp32 bias ball[896]
// from FLOAT32 inputs.  rows 0-255: w1/b1, 256-511: w2/b2, 512-767: w3/b3,
// rows 768-831: Wf/bf (fc folded conv branch), 832-895: zero pad.
// grid 896 x 256 threads.
// ---------------------------------------------------------------------------
__global__ __launch_bounds__(256) void k_build(const float* __restrict__ w1, const float* __restrict__ b1,
                                               const float* __restrict__ w2, const float* __restrict__ b2,
                                               const float* __restrict__ w3, const float* __restrict__ b3,
                                               const float* __restrict__ fcw,
                                               u16* __restrict__ Wall, float* __restrict__ ball){
  const int r = blockIdx.x, c = threadIdx.x;
  float v = 0.f, bv = 0.f;
  if (r < 256){      v = w1[(r << 8) + c];          bv = b1[r]; }
  else if (r < 512){ v = w2[((r - 256) << 8) + c];  bv = b2[r - 256]; }
  else if (r < 768){ v = w3[((r - 512) << 8) + c];  bv = b3[r - 512]; }
  else if (r < 832){
    const int d = r - 768;
    float s = 0.f, sbias = 0.f;
#pragma unroll
    for (int h = 0; h < 4; ++h){
      const int ch = (h << 6) + d;
      const float f1 = fcw[h], f2 = fcw[4 + h], f3 = fcw[8 + h];
      s     += f1 * w1[(ch << 8) + c] + f2 * w2[(ch << 8) + c] + f3 * w3[(ch << 8) + c];
      sbias += f1 * b1[ch] + f2 * b2[ch] + f3 * b3[ch];
    }
    v = s; bv = sbias;
  }
  Wall[(r << 8) + c] = f2b(v);
  if (c == 0) ball[r] = bv;
}

// ---------------------------------------------------------------------------
// K1: GEMM  qkvt[b][w][m] = Wall[m][:] . xt[b][w][:] + ball[m],  m<832 stored.
// M=896 (7 tiles of 128), N=32768 (b,w; 128-col tiles), K=256 (BK=64).
// 256 threads = 4 waves in 2x2; each wave 64x64 via 4x4 grid of 16x16x32 MFMA.
// Register staging (uint4 global->LDS), plain LDS layout.  bf16 internal,
// fp32 accumulate -- well within the 2%-of-max test threshold.
// grid (7, 256).
// ---------------------------------------------------------------------------
__global__ __launch_bounds__(256) void gemm_qkv(const u16* __restrict__ Wall, const float* __restrict__ ball,
                                                const u16* __restrict__ xt, u16* __restrict__ qkvt){
  __shared__ __align__(16) u16 As[128 * 64];
  __shared__ __align__(16) u16 Bs[128 * 64];
  const int mt = blockIdx.x, nt = blockIdx.y;
  const int b = nt >> 6;
  const int w0 = (nt & 63) << 7;
  const int tid = threadIdx.x;
  const int wave = tid >> 6, lane = tid & 63;
  const int wy = wave >> 1, wx = wave & 1;
  const int m0 = mt << 7;
  const int quad = lane >> 4, l15 = lane & 15;
  f32x4 acc[4][4] = {};

  for (int kc = 0; kc < 256; kc += 64){
    // stage 128x64 A-tile and B-tile: 1024 16B-chunks each, 4 per thread
    uint4 ra[4], rb[4];
#pragma unroll
    for (int k = 0; k < 4; ++k){
      const int cid = tid + (k << 8);          // 0..1023
      const int row = cid >> 3, u = cid & 7;   // row<128, unit<8 (8 bf16 each)
      ra[k] = *(const uint4*)(Wall + ((m0 + row) << 8) + kc + (u << 3));
      rb[k] = *(const uint4*)(xt + (((size_t)((b << 13) + w0 + row)) << 8) + kc + (u << 3));
    }
    __syncthreads();   // previous iteration's LDS reads complete before overwrite
#pragma unroll
    for (int k = 0; k < 4; ++k){
      const int cid = tid + (k << 8);
      const int row = cid >> 3, u = cid & 7;
      *(uint4*)(As + (row << 6) + (u << 3)) = ra[k];
      *(uint4*)(Bs + (row << 6) + (u << 3)) = rb[k];
    }
    __syncthreads();
#pragma unroll
    for (int ks = 0; ks < 2; ++ks){
      bf16x8 av[4], bvv[4];
#pragma unroll
      for (int i = 0; i < 4; ++i){
        const int rowA = (wy << 6) + (i << 4) + l15;
        av[i] = *(const bf16x8*)(As + (rowA << 6) + (((ks << 2) + quad) << 3));
        const int rowB = (wx << 6) + (i << 4) + l15;
        bvv[i] = *(const bf16x8*)(Bs + (rowB << 6) + (((ks << 2) + quad) << 3));
      }
#pragma unroll
      for (int i = 0; i < 4; ++i)
#pragma unroll
        for (int j = 0; j < 4; ++j)
          acc[i][j] = __builtin_amdgcn_mfma_f32_16x16x32_bf16(av[i], bvv[j], acc[i][j], 0, 0, 0);
    }
  }

  // epilogue: D row = quad*4+reg (m), col = lane&15 (w).  4 consecutive m per lane -> 8B store.
#pragma unroll
  for (int i = 0; i < 4; ++i){
    const int m = m0 + (wy << 6) + (i << 4) + (quad << 2);
    if (m < 832){
      const float4 bias = *(const float4*)(ball + m);
#pragma unroll
      for (int j = 0; j < 4; ++j){
        const int w = w0 + (wx << 6) + (j << 4) + l15;
        f32x4 r = acc[i][j];
        u32 lo = (u32)f2b(r.x + bias.x) | ((u32)f2b(r.y + bias.y) << 16);
        u32 hi = (u32)f2b(r.z + bias.z) | ((u32)f2b(r.w + bias.w) << 16);
        uint2 val; val.x = lo; val.y = hi;
        *(uint2*)(qkvt + ((size_t)((b << 13) + w)) * 832 + m) = val;
      }
    }
  }
}

// ---------------------------------------------------------------------------
// K2: windowed attention (K_ATT=7, reflect pad) + folded conv branch + combine.
// One thread per (b,h,w).  grid (32 wtiles of 256, 4 heads, 4 b) x 256 threads.
// k/v staged per 32-channel half into ONE 16.7KB LDS buffer (rotation swizzle).
// q (128B) and f (32B) per-thread from contiguous qkvt row slices.
// FLOAT32 params (wp/depw/depb/rates) and FLOAT32 output stores (coalesced).
// ---------------------------------------------------------------------------
__global__ __launch_bounds__(256) void attn_out(const u16* __restrict__ qkvt, const float* __restrict__ wp,
                                                const float* __restrict__ depw, const float* __restrict__ depb,
                                                const float* __restrict__ r1p, const float* __restrict__ r2p,
                                                float* __restrict__ out){
  __shared__ __align__(16) u16 sb[262 * 32];
  __shared__ float wpL[64];
  const int wt = blockIdx.x, h = blockIdx.y, b = blockIdx.z;
  const int w0 = wt << 8;
  const int t = threadIdx.x;
  const int w = w0 + t;
  if (t < 64) wpL[t] = wp[t];

  const u16* rowp = qkvt + ((size_t)((b << 13) + w)) * 832;
  uint4 qreg[8];
#pragma unroll
  for (int j = 0; j < 8; ++j) qreg[j] = *(const uint4*)(rowp + (h << 6) + (j << 3));
  float fv[16];
  {
    uint4 f0 = *(const uint4*)(rowp + 768 + (h << 4));
    uint4 f1 = *(const uint4*)(rowp + 768 + (h << 4) + 8);
    fv[0] = b2f_lo(f0.x); fv[1] = b2f_hi(f0.x); fv[2]  = b2f_lo(f0.y); fv[3]  = b2f_hi(f0.y);
    fv[4] = b2f_lo(f0.z); fv[5] = b2f_hi(f0.z); fv[6]  = b2f_lo(f0.w); fv[7]  = b2f_hi(f0.w);
    fv[8] = b2f_lo(f1.x); fv[9] = b2f_hi(f1.x); fv[10] = b2f_lo(f1.y); fv[11] = b2f_hi(f1.y);
    fv[12]= b2f_lo(f1.z); fv[13]= b2f_hi(f1.z); fv[14] = b2f_lo(f1.w); fv[15] = b2f_hi(f1.w);
  }

  float att[7] = {0.f,0.f,0.f,0.f,0.f,0.f,0.f};
  float qd = 0.f;

  // --- phase A: att[kk] = q . k[w+kk-3]  (two 32-channel halves) ---
#pragma unroll
  for (int half = 0; half < 2; ++half){
    __syncthreads();
    for (int idx = t; idx < 262 * 4; idx += 256){
      const int row = idx >> 2, u = idx & 3;
      int wsrc = w0 - 3 + row;
      wsrc = wsrc < 0 ? -wsrc : (wsrc > 8191 ? 16382 - wsrc : wsrc);
      const uint4 d = *(const uint4*)(qkvt + ((size_t)((b << 13) + wsrc)) * 832 + 256 + (h << 6) + (half << 5) + (u << 3));
      *(uint4*)(sb + (row << 5) + (((u + (row >> 1)) & 3) << 3)) = d;
    }
    __syncthreads();
#pragma unroll
    for (int jj = 0; jj < 4; ++jj){
      const int j = (half << 2) + jj;
      float qf[8];
      {
        const uint4 q4 = qreg[j];
        qf[0] = b2f_lo(q4.x); qf[1] = b2f_hi(q4.x); qf[2] = b2f_lo(q4.y); qf[3] = b2f_hi(q4.y);
        qf[4] = b2f_lo(q4.z); qf[5] = b2f_hi(q4.z); qf[6] = b2f_lo(q4.w); qf[7] = b2f_hi(q4.w);
      }
#pragma unroll
      for (int e = 0; e < 8; ++e) qd += qf[e] * wpL[(j << 3) + e];
#pragma unroll
      for (int kk = 0; kk < 7; ++kk){
        const int r = t + kk;
        const uint4 kv = *(const uint4*)(sb + (r << 5) + (((jj + (r >> 1)) & 3) << 3));
        float a = att[kk];
        a += qf[0] * b2f_lo(kv.x) + qf[1] * b2f_hi(kv.x) + qf[2] * b2f_lo(kv.y) + qf[3] * b2f_hi(kv.y)
           + qf[4] * b2f_lo(kv.z) + qf[5] * b2f_hi(kv.z) + qf[6] * b2f_lo(kv.w) + qf[7] * b2f_hi(kv.w);
        att[kk] = a;
      }
    }
  }

  // --- positional term + scale + softmax over the 7-window ---
  const float locw = -1.f + (2.f / 8191.f) * (float)w;
  float mx = -1e30f;
#pragma unroll
  for (int kk = 0; kk < 7; ++kk){
    int wr = w + kk - 3;
    wr = wr < 0 ? -wr : (wr > 8191 ? 16382 - wr : wr);
    const float lr = -1.f + (2.f / 8191.f) * (float)wr;
    att[kk] = 0.125f * (att[kk] + (locw - lr) * qd);
    mx = fmaxf(mx, att[kk]);
  }
  float p[7]; float ssum = 0.f;
#pragma unroll
  for (int kk = 0; kk < 7; ++kk){ p[kk] = __expf(att[kk] - mx); ssum += p[kk]; }
  const float inv = 1.f / ssum;
#pragma unroll
  for (int kk = 0; kk < 7; ++kk) p[kk] *= inv;

  const float r1 = r1p[0];
  const float r2 = r2p[0];

  // --- phase B: out = rate1 * (P.V) + rate2 * (dep_w * f + dep_b) ---
#pragma unroll
  for (int half = 0; half < 2; ++half){
    __syncthreads();
    for (int idx = t; idx < 262 * 4; idx += 256){
      const int row = idx >> 2, u = idx & 3;
      int wsrc = w0 - 3 + row;
      wsrc = wsrc < 0 ? -wsrc : (wsrc > 8191 ? 16382 - wsrc : wsrc);
      const uint4 d = *(const uint4*)(qkvt + ((size_t)((b << 13) + wsrc)) * 832 + 512 + (h << 6) + (half << 5) + (u << 3));
      *(uint4*)(sb + (row << 5) + (((u + (row >> 1)) & 3) << 3)) = d;
    }
    __syncthreads();
#pragma unroll
    for (int jj = 0; jj < 4; ++jj){
      float o[8] = {0.f,0.f,0.f,0.f,0.f,0.f,0.f,0.f};
#pragma unroll
      for (int kk = 0; kk < 7; ++kk){
        const int r = t + kk;
        const uint4 vv = *(const uint4*)(sb + (r << 5) + (((jj + (r >> 1)) & 3) << 3));
        const float pk = p[kk];
        o[0] += pk * b2f_lo(vv.x); o[1] += pk * b2f_hi(vv.x);
        o[2] += pk * b2f_lo(vv.y); o[3] += pk * b2f_hi(vv.y);
        o[4] += pk * b2f_lo(vv.z); o[5] += pk * b2f_hi(vv.z);
        o[6] += pk * b2f_lo(vv.w); o[7] += pk * b2f_hi(vv.w);
      }
      const int dl0 = (half << 5) + (jj << 3);
#pragma unroll
      for (int e = 0; e < 8; ++e){
        const int dl = dl0 + e;
        const float oc = depw[(h << 6) + dl] * fv[dl >> 2] + depb[(h << 6) + dl];
        out[(((size_t)((b << 8) + (h << 6) + dl)) << 13) + w] = r1 * o[e] + r2 * oc;
      }
    }
  }
}

// ---------------------------------------------------------------------------
// launch
// ---------------------------------------------------------------------------
extern "C" void kernel_launch(void* const* d_in, const int* in_sizes, int n_in,
                              void* d_out, int out_size, void* d_ws, size_t ws_size,
                              hipStream_t stream){
  (void)in_sizes; (void)n_in; (void)out_size; (void)ws_size;
  const float* x    = (const float*)d_in[0];
  const float* w1   = (const float*)d_in[1];
  const float* b1   = (const float*)d_in[2];
  const float* w2   = (const float*)d_in[3];
  const float* b2   = (const float*)d_in[4];
  const float* w3   = (const float*)d_in[5];
  const float* b3   = (const float*)d_in[6];
  const float* wp   = (const float*)d_in[7];
  // d_in[8] = bp : cancels analytically (pe - unfolded pe), unused
  const float* fcw  = (const float*)d_in[9];
  const float* depw = (const float*)d_in[10];
  const float* depb = (const float*)d_in[11];
  const float* r1p  = (const float*)d_in[12];
  const float* r2p  = (const float*)d_in[13];
  float* out = (float*)d_out;

  char* ws = (char*)d_ws;
  u16*   xt   = (u16*)(ws);                    // 4*8192*256*2   = 16,777,216 B
  u16*   Wall = (u16*)(ws + 16777216);         // 896*256*2      =    458,752 B
  float* ball = (float*)(ws + 17235968);       // 896*4          =      3,584 B
  u16*   qkvt = (u16*)(ws + 17239552);         // 4*8192*832*2   = 54,525,952 B
                                               // total ~71.8 MB

  k_transpose<<<dim3(128, 4, 4), 256, 0, stream>>>(x, xt);
  k_build<<<dim3(896, 1, 1), 256, 0, stream>>>(w1, b1, w2, b2, w3, b3, fcw, Wall, ball);
  gemm_qkv<<<dim3(7, 256, 1), 256, 0, stream>>>(Wall, ball, xt, qkvt);
  attn_out<<<dim3(32, 4, 4), 256, 0, stream>>>(qkvt, wp, depw, depb, r1p, r2p, out);
}